// Round 9
// baseline (137.931 us; speedup 1.0000x reference)
//
#include <hip/hip_runtime.h>
#include <stdint.h>

typedef __attribute__((ext_vector_type(8))) short bf8v;   // 8 bf16/f16 raw bits (4 VGPRs)
typedef __attribute__((ext_vector_type(4))) float f4v;
typedef __attribute__((ext_vector_type(16))) float f16v;
typedef __attribute__((ext_vector_type(4))) unsigned int u4v;

__device__ __forceinline__ unsigned short f2bf(float f) {
  unsigned int u = __float_as_uint(f);
  u += 0x7fffu + ((u >> 16) & 1u);   // round-to-nearest-even
  return (unsigned short)(u >> 16);
}

__device__ __forceinline__ float bf2f(unsigned short s) {
  return __uint_as_float((unsigned)s << 16);
}

__device__ __forceinline__ unsigned short f2h(float f) {
  _Float16 h = (_Float16)f;
  return __builtin_bit_cast(unsigned short, h);
}

__device__ __forceinline__ float h2f(unsigned short s) {
  return (float)__builtin_bit_cast(_Float16, s);
}

__device__ __forceinline__ void gload16(const void* g, void* l) {
  __builtin_amdgcn_global_load_lds(
      (__attribute__((address_space(1))) void*)reinterpret_cast<uintptr_t>(g),
      (__attribute__((address_space(3))) void*)reinterpret_cast<uintptr_t>(l),
      16, 0, 0);
}

__device__ __forceinline__ unsigned cvtpk(float lo, float hi) {
  unsigned r;
  asm("v_cvt_pk_bf16_f32 %0, %1, %2" : "=v"(r) : "v"(lo), "v"(hi));
  return r;
}

// pairwise lane<->lane^32 exchange; with x=y=v: x={v.lo,v.lo}, y={v.hi,v.hi}
#define PAIR_SWAP(x, y) asm("v_permlane32_swap_b32 %0, %1" : "+v"(x), "+v"(y))

// ---------------- fp32 -> bf16 conversion (single fused launch) ----------------
__global__ __launch_bounds__(256) void cvt_all(
    const float* __restrict__ s0, const float* __restrict__ s1,
    const float* __restrict__ s2, const float* __restrict__ s3,
    const float* __restrict__ s4, const float* __restrict__ s5,
    const float* __restrict__ s6, unsigned short* __restrict__ dst) {
  const size_t NA = (size_t)1 << 22, NW = (size_t)1 << 20;
  size_t i = ((size_t)blockIdx.x * 256 + threadIdx.x) * 8;
  const float* src;
  size_t off;
  if (i < 3 * NA) {
    int a = (int)(i >> 22);
    src = (a == 0) ? s0 : (a == 1) ? s1 : s2;
    off = i & (NA - 1);
  } else {
    size_t j = i - 3 * NA;
    int a = (int)(j >> 20);
    src = (a == 0) ? s3 : (a == 1) ? s4 : (a == 2) ? s5 : s6;
    off = j & (NW - 1);
  }
  const f4v* sp = (const f4v*)(src + off);
  f4v x = sp[0], y = sp[1];
  bf8v r;
  r[0] = (short)f2bf(x[0]); r[1] = (short)f2bf(x[1]);
  r[2] = (short)f2bf(x[2]); r[3] = (short)f2bf(x[3]);
  r[4] = (short)f2bf(y[0]); r[5] = (short)f2bf(y[1]);
  r[6] = (short)f2bf(y[2]); r[7] = (short)f2bf(y[3]);
  *(bf8v*)(dst + i) = r;
}

// ---------------- 128xTNx(BK=32) bf16 GEMM body (m97 structure) ----------------
template <int OMODE, int TN>
__device__ __forceinline__ void gemm_body(
    unsigned short* Al, unsigned short* Bl,
    const unsigned short* __restrict__ A, const unsigned short* __restrict__ W,
    const float* __restrict__ bias, void* __restrict__ out) {
  const int tid = threadIdx.x;
  const int w = tid >> 6, l = tid & 63;
  const int lr = l >> 4, lc = l & 15;
  const int m0 = blockIdx.x * 128, n0 = blockIdx.y * TN;
  const int wr = w >> 1, wc = w & 1;
  const int JW = TN / 32;
  const int BCPW = TN / 64;
  const int BBUF = TN * 32;

  f4v acc[4][JW];
#pragma unroll
  for (int i = 0; i < 4; i++)
#pragma unroll
    for (int j = 0; j < JW; j++) acc[i][j] = (f4v)(0.0f);

  const int NK = 32;
#pragma unroll
  for (int i = 0; i < 2; i++) {
    int chunk = w * 2 + i;
    int e = chunk * 512 + l * 8;
    int r = e >> 5, k = e & 31;
    gload16(A + (size_t)(m0 + r) * 1024 + k, Al + chunk * 512);
  }
#pragma unroll
  for (int i = 0; i < BCPW; i++) {
    int chunk = w * BCPW + i;
    int e = chunk * 512 + l * 8;
    int r = e >> 5, k = e & 31;
    gload16(W + (size_t)(n0 + r) * 1024 + k, Bl + chunk * 512);
  }

  for (int kk = 0; kk < NK; kk++) {
    const int cur = kk & 1;
    __syncthreads();
    if (kk + 1 < NK) {
#pragma unroll
      for (int i = 0; i < 2; i++) {
        int chunk = w * 2 + i;
        int e = chunk * 512 + l * 8;
        int r = e >> 5, k = (kk + 1) * 32 + (e & 31);
        gload16(A + (size_t)(m0 + r) * 1024 + k, Al + (cur ^ 1) * 4096 + chunk * 512);
      }
#pragma unroll
      for (int i = 0; i < BCPW; i++) {
        int chunk = w * BCPW + i;
        int e = chunk * 512 + l * 8;
        int r = e >> 5, k = (kk + 1) * 32 + (e & 31);
        gload16(W + (size_t)(n0 + r) * 1024 + k, Bl + (cur ^ 1) * BBUF + chunk * 512);
      }
    }
    bf8v av[4], bv[JW];
#pragma unroll
    for (int i = 0; i < 4; i++) {
      int row = wr * 64 + i * 16 + lc;
      av[i] = *(const bf8v*)(Al + cur * 4096 + row * 32 + lr * 8);
    }
#pragma unroll
    for (int j = 0; j < JW; j++) {
      int row = wc * (TN / 2) + j * 16 + lc;
      bv[j] = *(const bf8v*)(Bl + cur * BBUF + row * 32 + lr * 8);
    }
#pragma unroll
    for (int i = 0; i < 4; i++)
#pragma unroll
      for (int j = 0; j < JW; j++)
        acc[i][j] = __builtin_amdgcn_mfma_f32_16x16x32_bf16(av[i], bv[j], acc[i][j], 0, 0, 0);
  }

#pragma unroll
  for (int j = 0; j < JW; j++) {
    int n = n0 + wc * (TN / 2) + j * 16 + lc;
    float bj = bias[n];
#pragma unroll
    for (int i = 0; i < 4; i++) {
      int mb = m0 + wr * 64 + i * 16 + lr * 4;
#pragma unroll
      for (int q = 0; q < 4; q++) {
        float val = fmaxf(acc[i][j][q] + bj, 0.0f);
        int m = mb + q;
        if (OMODE == 2) {
          int s = m & 2047, b = m >> 11;
          ((float*)out)[(size_t)(s * 2 + b) * 1024 + n] = val;
        } else {
          int s = m >> 1, b = m & 1;
          int h = n >> 6, d = n & 63;
          if (OMODE == 0)
            ((unsigned short*)out)[((size_t)(b * 16 + h) * 2048 + s) * 64 + d] = f2bf(val);
          else
            ((unsigned short*)out)[((size_t)(b * 16 + h) * 64 + d) * 2048 + s] = f2bf(val);
        }
      }
    }
  }
}

__global__ __launch_bounds__(256) void qkv_gemm(
    const unsigned short* __restrict__ qA, const unsigned short* __restrict__ kA,
    const unsigned short* __restrict__ vA,
    const unsigned short* __restrict__ Wq, const unsigned short* __restrict__ Wk,
    const unsigned short* __restrict__ Wv,
    const float* __restrict__ bq, const float* __restrict__ bk,
    const float* __restrict__ bv,
    unsigned short* __restrict__ Qh, unsigned short* __restrict__ Kh,
    unsigned short* __restrict__ Vt) {
  __shared__ __align__(16) unsigned short Al[2 * 4096];
  __shared__ __align__(16) unsigned short Bl[2 * 4096];
  int z = blockIdx.z;
  if (z == 0)      gemm_body<0, 128>(Al, Bl, qA, Wq, bq, Qh);
  else if (z == 1) gemm_body<0, 128>(Al, Bl, kA, Wk, bk, Kh);
  else             gemm_body<1, 128>(Al, Bl, vA, Wv, bv, Vt);
}

__global__ __launch_bounds__(256) void out_gemm(
    const unsigned short* __restrict__ Y, const unsigned short* __restrict__ Wo,
    const float* __restrict__ bo, float* __restrict__ out) {
  __shared__ __align__(16) unsigned short Al[2 * 4096];
  __shared__ __align__(16) unsigned short Bl[2 * 2048];
  gemm_body<2, 64>(Al, Bl, Y, Wo, bo, out);
}

// ---------------- flash attention v9: dual-subtile waves + KV-split x4 (ws check fixed) ----------------
// Identical kernel to R8; only the launch-side SPL selection changed (R8's
// need4 was wrongly 384MB -> silent SPL=2 fallback; actual need is 98MB).
__global__ __launch_bounds__(256, 2) void attn_kernel(
    const unsigned short* __restrict__ Qh, const unsigned short* __restrict__ Kh,
    const unsigned short* __restrict__ Vt,
    unsigned short* __restrict__ PO, float2* __restrict__ ML, int kvlen) {
  __shared__ __align__(16) unsigned short Kl[2][4096];
  __shared__ __align__(16) unsigned short Vl[2][4096];
  const int tid = threadIdx.x, w = tid >> 6, l = tid & 63;
  const int lo = l & 31, hi = l >> 5;
  const int bh = blockIdx.y;
  const int z = blockIdx.z;
  const int tbeg = z * kvlen, tend = tbeg + kvlen;
  const int q0 = blockIdx.x * 256 + w * 64;
  const size_t qkbase = (size_t)bh * 2048 * 64;
  const size_t vtbase = (size_t)bh * 64 * 2048;
  const float cs = 0.125f * 1.44269504088896341f;  // 1/sqrt(64) * log2(e)

  // Q fragments (B-operand): lane holds Q[q0+s*32+lo][c*16+hi*8 ..+8]
  bf8v qf[2][4];
#pragma unroll
  for (int s = 0; s < 2; s++)
#pragma unroll
    for (int c = 0; c < 4; c++)
      qf[s][c] = *(const bf8v*)(Qh + qkbase + (size_t)(q0 + s * 32 + lo) * 64 + c * 16 + hi * 8);

  f16v oacc[2][2];
  oacc[0][0] = (f16v)(0.0f); oacc[0][1] = (f16v)(0.0f);
  oacc[1][0] = (f16v)(0.0f); oacc[1][1] = (f16v)(0.0f);
  float mrun[2] = {-1e30f, -1e30f};
  float lrun[2] = {0.0f, 0.0f};          // per-lane half-sums

  // LDS read byte-addresses, swizzle (lo&7)<<4
  const int swl = (lo & 7) << 4;
  int akb[4], avb[2][2][2];
#pragma unroll
  for (int c = 0; c < 4; c++) akb[c] = lo * 128 + ((c * 32 + hi * 16) ^ swl);
#pragma unroll
  for (int dt = 0; dt < 2; dt++)
#pragma unroll
    for (int kvh = 0; kvh < 2; kvh++)
#pragma unroll
      for (int kc = 0; kc < 2; kc++)
        avb[dt][kvh][kc] = (dt * 32 + lo) * 128 + ((kvh * 64 + kc * 32 + hi * 16) ^ swl);

  // staging source elements (pre-swizzled: linear LDS dest + swizzled read match)
  int stE[2], stD[2], stKV[2];
#pragma unroll
  for (int i = 0; i < 2; i++) {
    int o = (w * 2 + i) * 1024 + l * 16;
    int row = o >> 7;
    stE[i] = (o ^ ((row & 7) << 4)) >> 1;
    stD[i] = stE[i] >> 6;
    stKV[i] = stE[i] & 63;
  }
  const char* KlB = (const char*)&Kl[0][0];
  const char* VlB = (const char*)&Vl[0][0];

  auto STAGE = [&](int buf, int t0) {
#pragma unroll
    for (int i = 0; i < 2; i++) {
      gload16(Kh + qkbase + (size_t)t0 * 64 + stE[i], (char*)&Kl[buf][0] + (w * 2 + i) * 1024);
      gload16(Vt + vtbase + (size_t)stD[i] * 2048 + t0 + stKV[i], (char*)&Vl[buf][0] + (w * 2 + i) * 1024);
    }
  };

  auto COMPUTE = [&](int bo) {
#pragma unroll
    for (int kvh = 0; kvh < 2; kvh++) {
      // K fragments (A-operand), shared by both q-subtiles
      bf8v kf[4];
#pragma unroll
      for (int c = 0; c < 4; c++)
        kf[c] = *(const bf8v*)(KlB + bo + kvh * 4096 + akb[c]);
      f16v sa = (f16v)(0.0f), sb = (f16v)(0.0f);
      __builtin_amdgcn_s_setprio(1);
#pragma unroll
      for (int c = 0; c < 4; c++) {
        sa = __builtin_amdgcn_mfma_f32_32x32x16_bf16(kf[c], qf[0][c], sa, 0, 0, 0);
        sb = __builtin_amdgcn_mfma_f32_32x32x16_bf16(kf[c], qf[1][c], sb, 0, 0, 0);
      }
      __builtin_amdgcn_s_setprio(0);
      // V^T fragments (A-operand), shared by both q-subtiles
      bf8v vf[2][2];
#pragma unroll
      for (int dt = 0; dt < 2; dt++)
#pragma unroll
        for (int kc = 0; kc < 2; kc++)
          vf[dt][kc] = *(const bf8v*)(VlB + bo + avb[dt][kvh][kc]);

#pragma unroll
      for (int s = 0; s < 2; s++) {
        const f16v& sc16 = (s == 0) ? sa : sb;
        // in-lane local max (max3-fusable triples)
        float t0 = fmaxf(fmaxf(sc16[0], sc16[1]), sc16[2]);
        float t1 = fmaxf(fmaxf(sc16[3], sc16[4]), sc16[5]);
        float t2 = fmaxf(fmaxf(sc16[6], sc16[7]), sc16[8]);
        float t3 = fmaxf(fmaxf(sc16[9], sc16[10]), sc16[11]);
        float t4 = fmaxf(fmaxf(sc16[12], sc16[13]), sc16[14]);
        float lm = fmaxf(fmaxf(fmaxf(t0, t1), fmaxf(t2, t3)), fmaxf(t4, sc16[15]));
        float msc = lm * cs;
        // T13 with LOCAL max: row max = max over the q-row's two lanes, both
        // covered by __all -> bound holds without any cross-lane op.
        if (!__all(msc <= mrun[s] + 5.0f)) {
          float x = msc, y = msc;
          PAIR_SWAP(x, y);
          float pm = fmaxf(x, y);              // exact pair (q-row) max
          float mnew = fmaxf(mrun[s], pm);
          float scl = __builtin_amdgcn_exp2f(mrun[s] - mnew);
          lrun[s] *= scl;
#pragma unroll
          for (int dt = 0; dt < 2; dt++)
#pragma unroll
            for (int r = 0; r < 16; r++) oacc[s][dt][r] *= scl;
          mrun[s] = mnew;
        }
        float p[16];
#pragma unroll
        for (int r = 0; r < 16; r++)
          p[r] = __builtin_amdgcn_exp2f(sc16[r] * cs - mrun[s]);
        // pairwise sum tree, off the PV critical path
        float s01 = (p[0] + p[1]) + (p[2] + p[3]);
        float s23 = (p[4] + p[5]) + (p[6] + p[7]);
        float s45 = (p[8] + p[9]) + (p[10] + p[11]);
        float s67 = (p[12] + p[13]) + (p[14] + p[15]);
        lrun[s] += (s01 + s23) + (s45 + s67);
        // T12: pack to bf16 + permlane32_swap -> P^T B-operand fragments
        bf8v pf[2];
#pragma unroll
        for (int kc = 0; kc < 2; kc++) {
          unsigned a0 = cvtpk(p[kc * 8 + 0], p[kc * 8 + 1]);
          unsigned a1 = cvtpk(p[kc * 8 + 2], p[kc * 8 + 3]);
          unsigned b0 = cvtpk(p[kc * 8 + 4], p[kc * 8 + 5]);
          unsigned b1 = cvtpk(p[kc * 8 + 6], p[kc * 8 + 7]);
          PAIR_SWAP(a0, b0);
          PAIR_SWAP(a1, b1);
          u4v pw;
          pw[0] = a0; pw[1] = a1; pw[2] = b0; pw[3] = b1;
          pf[kc] = __builtin_bit_cast(bf8v, pw);
        }
        __builtin_amdgcn_s_setprio(1);
#pragma unroll
        for (int dt = 0; dt < 2; dt++)
#pragma unroll
          for (int kc = 0; kc < 2; kc++)
            oacc[s][dt] = __builtin_amdgcn_mfma_f32_32x32x16_bf16(vf[dt][kc], pf[kc],
                                                                 oacc[s][dt], 0, 0, 0);
        __builtin_amdgcn_s_setprio(0);
      }
    }
  };

  STAGE(0, tbeg);
  __syncthreads();
#pragma unroll 1
  for (int t0 = tbeg; t0 < tend; t0 += 128) {
    STAGE(1, t0 + 64);
    COMPUTE(0);
    __syncthreads();
    if (t0 + 128 < tend) STAGE(0, t0 + 128);
    COMPUTE(8192);
    __syncthreads();
  }

  // epilogue: combine per-lane half-sums, NORMALIZE, write fp16 partials.
#pragma unroll
  for (int s = 0; s < 2; s++) {
    float x = lrun[s], y = lrun[s];
    PAIR_SWAP(x, y);
    float lt = x + y;                       // pair-total row sum
    float inv = 1.0f / lt;
    int q = q0 + s * 32 + lo;
    size_t prow = (size_t)(z * 32 + bh) * 2048 + q;
    if (hi == 0) ML[prow] = float2{mrun[s], lt};
    unsigned short* pp = PO + prow * 64;
#pragma unroll
    for (int dt = 0; dt < 2; dt++)
#pragma unroll
      for (int r = 0; r < 16; r++) {
        int d = dt * 32 + (r & 3) + 8 * (r >> 2) + 4 * hi;
        pp[d] = f2h(oacc[s][dt][r] * inv);
      }
  }
}

// ---------------- combine SPL normalized fp16 partials -> Y (B,S,D) bf16 ----------------
template <int SPL>
__global__ __launch_bounds__(256) void combine_kernel(
    const unsigned short* __restrict__ PO, const float2* __restrict__ ML,
    unsigned short* __restrict__ Y) {
  int idx = blockIdx.x * 256 + threadIdx.x;
  int row = idx >> 1, hr = idx & 1;
  int bh = row >> 11, q = row & 2047;
  float2 ml[SPL];
  float M = -1e30f;
#pragma unroll
  for (int i = 0; i < SPL; i++) {
    ml[i] = ML[i * 65536 + row];
    M = fmaxf(M, ml[i].x);
  }
  float wgt[SPL], W = 0.0f;
#pragma unroll
  for (int i = 0; i < SPL; i++) {
    wgt[i] = ml[i].y * __builtin_amdgcn_exp2f(ml[i].x - M);
    W += wgt[i];
  }
  float invW = 1.0f / W;
#pragma unroll
  for (int i = 0; i < SPL; i++) wgt[i] *= invW;
  int b = bh >> 4, h = bh & 15;
  unsigned short* yp = Y + (((size_t)(b * 2048 + q)) << 10) + h * 64 + hr * 32;
#pragma unroll
  for (int g = 0; g < 4; g++) {
    float accv[8];
#pragma unroll
    for (int j = 0; j < 8; j++) accv[j] = 0.0f;
#pragma unroll
    for (int i = 0; i < SPL; i++) {
      bf8v v = *(const bf8v*)(PO + ((size_t)i * 65536 + row) * 64 + hr * 32 + g * 8);
#pragma unroll
      for (int j = 0; j < 8; j++) accv[j] += h2f((unsigned short)v[j]) * wgt[i];
    }
    bf8v r;
#pragma unroll
    for (int j = 0; j < 8; j++) r[j] = (short)f2bf(accv[j]);
    *(bf8v*)(yp + g * 8) = r;
  }
}

// ---------------- launch ----------------
extern "C" void kernel_launch(void* const* d_in, const int* in_sizes, int n_in,
                              void* d_out, int out_size, void* d_ws, size_t ws_size,
                              hipStream_t stream) {
  const float* q  = (const float*)d_in[0];
  const float* k  = (const float*)d_in[1];
  const float* v  = (const float*)d_in[2];
  const float* Wq = (const float*)d_in[3];
  const float* Wk = (const float*)d_in[4];
  const float* Wv = (const float*)d_in[5];
  const float* Wo = (const float*)d_in[6];
  const float* bq = (const float*)d_in[7];
  const float* bk = (const float*)d_in[8];
  const float* bv = (const float*)d_in[9];
  const float* bo = (const float*)d_in[10];

  const size_t NA = (size_t)4096 * 1024;   // 4M elems
  const size_t NW = (size_t)1024 * 1024;
  unsigned short* qA  = (unsigned short*)d_ws;   // cvt dst: q,k,v,Wq,Wk,Wv,Wo contiguous
  unsigned short* kA  = qA  + NA;
  unsigned short* vA  = kA  + NA;
  unsigned short* WqB = vA  + NA;
  unsigned short* WkB = WqB + NW;
  unsigned short* WvB = WkB + NW;
  unsigned short* WoB = WvB + NW;
  unsigned short* Qh  = WoB + NW;
  unsigned short* Kh  = Qh  + NA;
  unsigned short* Vt  = Kh  + NA;
  unsigned short* Y   = Vt  + NA;                // base region: 32M elems = 64 MB

  // SPL=4 needs base(32M elems=64MB) + PO(4*NA fp16=32MB) + ML(2MB) = 98MB.
  // (R8 bug: need4 was computed as 384MB -> silent SPL=2 fallback.)
  const size_t need4 = (8 * NA + 4 * NA) * sizeof(unsigned short)   // base + PO
                     + (size_t)4 * 65536 * sizeof(float2) + 4096;   // ML + pad
  int SPL;
  unsigned short* PO;
  float2* ML;
  if (ws_size >= need4) {
    SPL = 4;
    PO = Y + NA;                         // 4 * 4M fp16 = 32 MB
    ML = (float2*)(PO + 4 * NA);         // 4 * 64K float2 = 2 MB
  } else {
    SPL = 2;
    PO = qA;                             // 2 * 4M fp16 = 16 MB (dead region)
    ML = (float2*)vA;
  }

  cvt_all<<<dim3(8192), 256, 0, stream>>>(q, k, v, Wq, Wk, Wv, Wo, qA);

  qkv_gemm<<<dim3(32, 8, 3), 256, 0, stream>>>(qA, kA, vA, WqB, WkB, WvB,
                                               bq, bk, bv, Qh, Kh, Vt);
  attn_kernel<<<dim3(8, 32, SPL), 256, 0, stream>>>(Qh, Kh, Vt, PO, ML, 2048 / SPL);
  if (SPL == 4)
    combine_kernel<4><<<dim3(512), 256, 0, stream>>>(PO, ML, Y);
  else
    combine_kernel<2><<<dim3(512), 256, 0, stream>>>(PO, ML, Y);
  out_gemm<<<dim3(32, 16), 256, 0, stream>>>(Y, WoB, bo, (float*)d_out);
}

// Round 10
// 127.545 us; speedup vs baseline: 1.0814x; 1.0814x over previous
//
#include <hip/hip_runtime.h>
#include <stdint.h>

typedef __attribute__((ext_vector_type(8))) short bf8v;   // 8 bf16/f16 raw bits (4 VGPRs)
typedef __attribute__((ext_vector_type(4))) float f4v;
typedef __attribute__((ext_vector_type(16))) float f16v;
typedef __attribute__((ext_vector_type(4))) unsigned int u4v;

__device__ __forceinline__ unsigned short f2bf(float f) {
  unsigned int u = __float_as_uint(f);
  u += 0x7fffu + ((u >> 16) & 1u);   // round-to-nearest-even
  return (unsigned short)(u >> 16);
}

__device__ __forceinline__ unsigned short f2h(float f) {
  _Float16 h = (_Float16)f;
  return __builtin_bit_cast(unsigned short, h);
}

__device__ __forceinline__ float h2f(unsigned short s) {
  return (float)__builtin_bit_cast(_Float16, s);
}

__device__ __forceinline__ void gload16(const void* g, void* l) {
  __builtin_amdgcn_global_load_lds(
      (__attribute__((address_space(1))) void*)reinterpret_cast<uintptr_t>(g),
      (__attribute__((address_space(3))) void*)reinterpret_cast<uintptr_t>(l),
      16, 0, 0);
}

__device__ __forceinline__ unsigned cvtpk(float lo, float hi) {
  unsigned r;
  asm("v_cvt_pk_bf16_f32 %0, %1, %2" : "=v"(r) : "v"(lo), "v"(hi));
  return r;
}

// pairwise lane<->lane^32 exchange; with x=y=v: x={v.lo,v.lo}, y={v.hi,v.hi}
#define PAIR_SWAP(x, y) asm("v_permlane32_swap_b32 %0, %1" : "+v"(x), "+v"(y))

// ---------------- fp32 -> bf16 conversion: WEIGHTS ONLY (4 x 1M elems) ----------------
__global__ __launch_bounds__(256) void cvt_w(
    const float* __restrict__ s0, const float* __restrict__ s1,
    const float* __restrict__ s2, const float* __restrict__ s3,
    unsigned short* __restrict__ dst) {
  const size_t NW = (size_t)1 << 20;
  size_t i = ((size_t)blockIdx.x * 256 + threadIdx.x) * 8;
  int a = (int)(i >> 20);
  const float* src = (a == 0) ? s0 : (a == 1) ? s1 : (a == 2) ? s2 : s3;
  size_t off = i & (NW - 1);
  const f4v* sp = (const f4v*)(src + off);
  f4v x = sp[0], y = sp[1];
  bf8v r;
  r[0] = (short)f2bf(x[0]); r[1] = (short)f2bf(x[1]);
  r[2] = (short)f2bf(x[2]); r[3] = (short)f2bf(x[3]);
  r[4] = (short)f2bf(y[0]); r[5] = (short)f2bf(y[1]);
  r[6] = (short)f2bf(y[2]); r[7] = (short)f2bf(y[3]);
  *(bf8v*)(dst + i) = r;
}

// ---------------- fused-cvt GEMM: A fp32 (staged+swizzled), W bf16 ----------------
// A: (4096,1024) fp32 row-major (rows m = s*2+b).  W: (1024,1024) bf16 (n,k).
// A-LDS: fp32 [128][32] = 16KB/buffer, XOR-swizzled ((row&7)<<4 on byte addr,
// 128B rows) via pre-swizzled global source (rule #21) -> fragment ds_read_b128
// pairs are conflict-free. Fragments cvt_pk'd to bf16 in-register before MFMA.
// OMODE 0: out bf16 (B,H,S,64).  OMODE 1: out bf16 (B,H,64,S) [V transposed].
template <int OMODE>
__device__ __forceinline__ void gemmA32_body(
    float* Al, unsigned short* Bl,
    const float* __restrict__ A, const unsigned short* __restrict__ W,
    const float* __restrict__ bias, unsigned short* __restrict__ out) {
  const int tid = threadIdx.x;
  const int w = tid >> 6, l = tid & 63;
  const int lr = l >> 4, lc = l & 15;
  const int m0 = blockIdx.x * 128, n0 = blockIdx.y * 128;
  const int wr = w >> 1, wc = w & 1;

  f4v acc[4][4];
#pragma unroll
  for (int i = 0; i < 4; i++)
#pragma unroll
    for (int j = 0; j < 4; j++) acc[i][j] = (f4v)(0.0f);

  // staging source indices (A: pre-swizzled fp32; B: linear bf16)
  int aR[4], aK[4];
#pragma unroll
  for (int i = 0; i < 4; i++) {
    int o = (w * 4 + i) * 1024 + l * 16;       // dest byte in 16KB tile
    int row = o >> 7;                          // 128B rows
    int e = (o ^ ((row & 7) << 4)) >> 2;       // fp32 elem (inverse-swizzled)
    aR[i] = e >> 5; aK[i] = e & 31;
  }

  const int NK = 32;
#pragma unroll
  for (int i = 0; i < 4; i++)
    gload16(A + (size_t)(m0 + aR[i]) * 1024 + aK[i], (char*)Al + (w * 4 + i) * 1024);
#pragma unroll
  for (int i = 0; i < 2; i++) {
    int chunk = w * 2 + i;
    int e = chunk * 512 + l * 8;
    int r = e >> 5, k = e & 31;
    gload16(W + (size_t)(n0 + r) * 1024 + k, Bl + chunk * 512);
  }

  for (int kk = 0; kk < NK; kk++) {
    const int cur = kk & 1;
    __syncthreads();
    if (kk + 1 < NK) {
#pragma unroll
      for (int i = 0; i < 4; i++)
        gload16(A + (size_t)(m0 + aR[i]) * 1024 + (kk + 1) * 32 + aK[i],
                (char*)Al + (cur ^ 1) * 16384 + (w * 4 + i) * 1024);
#pragma unroll
      for (int i = 0; i < 2; i++) {
        int chunk = w * 2 + i;
        int e = chunk * 512 + l * 8;
        int r = e >> 5, k = (kk + 1) * 32 + (e & 31);
        gload16(W + (size_t)(n0 + r) * 1024 + k, Bl + (cur ^ 1) * 4096 + chunk * 512);
      }
    }
    const char* AlB = (const char*)Al + cur * 16384;
    bf8v av[4], bv[4];
#pragma unroll
    for (int i = 0; i < 4; i++) {
      int row = wr * 64 + i * 16 + lc;
      int b0 = (row * 128 + lr * 32) ^ ((row & 7) << 4);
      f4v x = *(const f4v*)(AlB + b0);
      f4v y = *(const f4v*)(AlB + (b0 ^ 16));
      u4v aw;
      aw[0] = cvtpk(x[0], x[1]); aw[1] = cvtpk(x[2], x[3]);
      aw[2] = cvtpk(y[0], y[1]); aw[3] = cvtpk(y[2], y[3]);
      av[i] = __builtin_bit_cast(bf8v, aw);
    }
#pragma unroll
    for (int j = 0; j < 4; j++) {
      int row = wc * 64 + j * 16 + lc;
      bv[j] = *(const bf8v*)(Bl + cur * 4096 + row * 32 + lr * 8);
    }
#pragma unroll
    for (int i = 0; i < 4; i++)
#pragma unroll
      for (int j = 0; j < 4; j++)
        acc[i][j] = __builtin_amdgcn_mfma_f32_16x16x32_bf16(av[i], bv[j], acc[i][j], 0, 0, 0);
  }

#pragma unroll
  for (int j = 0; j < 4; j++) {
    int n = n0 + wc * 64 + j * 16 + lc;
    float bj = bias[n];
#pragma unroll
    for (int i = 0; i < 4; i++) {
      int mb = m0 + wr * 64 + i * 16 + lr * 4;
#pragma unroll
      for (int q = 0; q < 4; q++) {
        float val = fmaxf(acc[i][j][q] + bj, 0.0f);
        int m = mb + q;
        int s = m >> 1, b = m & 1;
        int h = n >> 6, d = n & 63;
        if (OMODE == 0)
          out[((size_t)(b * 16 + h) * 2048 + s) * 64 + d] = f2bf(val);
        else
          out[((size_t)(b * 16 + h) * 64 + d) * 2048 + s] = f2bf(val);
      }
    }
  }
}

__global__ __launch_bounds__(256) void qkv_gemm(
    const float* __restrict__ qA, const float* __restrict__ kA,
    const float* __restrict__ vA,
    const unsigned short* __restrict__ Wq, const unsigned short* __restrict__ Wk,
    const unsigned short* __restrict__ Wv,
    const float* __restrict__ bq, const float* __restrict__ bk,
    const float* __restrict__ bv,
    unsigned short* __restrict__ Qh, unsigned short* __restrict__ Kh,
    unsigned short* __restrict__ Vt) {
  __shared__ __align__(16) float Al[2 * 4096];            // 32 KB
  __shared__ __align__(16) unsigned short Bl[2 * 4096];   // 16 KB
  int z = blockIdx.z;
  if (z == 0)      gemmA32_body<0>(Al, Bl, qA, Wq, bq, Qh);
  else if (z == 1) gemmA32_body<0>(Al, Bl, kA, Wk, bk, Kh);
  else             gemmA32_body<1>(Al, Bl, vA, Wv, bv, Vt);
}

// ---------------- bf16-A GEMM body (m97 structure), used by out_gemm ----------------
template <int TN>
__device__ __forceinline__ void gemm_body2(
    unsigned short* Al, unsigned short* Bl,
    const unsigned short* __restrict__ A, const unsigned short* __restrict__ W,
    const float* __restrict__ bias, float* __restrict__ out) {
  const int tid = threadIdx.x;
  const int w = tid >> 6, l = tid & 63;
  const int lr = l >> 4, lc = l & 15;
  const int m0 = blockIdx.x * 128, n0 = blockIdx.y * TN;
  const int wr = w >> 1, wc = w & 1;
  const int JW = TN / 32;
  const int BCPW = TN / 64;
  const int BBUF = TN * 32;

  f4v acc[4][JW];
#pragma unroll
  for (int i = 0; i < 4; i++)
#pragma unroll
    for (int j = 0; j < JW; j++) acc[i][j] = (f4v)(0.0f);

  const int NK = 32;
#pragma unroll
  for (int i = 0; i < 2; i++) {
    int chunk = w * 2 + i;
    int e = chunk * 512 + l * 8;
    int r = e >> 5, k = e & 31;
    gload16(A + (size_t)(m0 + r) * 1024 + k, Al + chunk * 512);
  }
#pragma unroll
  for (int i = 0; i < BCPW; i++) {
    int chunk = w * BCPW + i;
    int e = chunk * 512 + l * 8;
    int r = e >> 5, k = e & 31;
    gload16(W + (size_t)(n0 + r) * 1024 + k, Bl + chunk * 512);
  }

  for (int kk = 0; kk < NK; kk++) {
    const int cur = kk & 1;
    __syncthreads();
    if (kk + 1 < NK) {
#pragma unroll
      for (int i = 0; i < 2; i++) {
        int chunk = w * 2 + i;
        int e = chunk * 512 + l * 8;
        int r = e >> 5, k = (kk + 1) * 32 + (e & 31);
        gload16(A + (size_t)(m0 + r) * 1024 + k, Al + (cur ^ 1) * 4096 + chunk * 512);
      }
#pragma unroll
      for (int i = 0; i < BCPW; i++) {
        int chunk = w * BCPW + i;
        int e = chunk * 512 + l * 8;
        int r = e >> 5, k = (kk + 1) * 32 + (e & 31);
        gload16(W + (size_t)(n0 + r) * 1024 + k, Bl + (cur ^ 1) * BBUF + chunk * 512);
      }
    }
    bf8v av[4], bv[JW];
#pragma unroll
    for (int i = 0; i < 4; i++) {
      int row = wr * 64 + i * 16 + lc;
      av[i] = *(const bf8v*)(Al + cur * 4096 + row * 32 + lr * 8);
    }
#pragma unroll
    for (int j = 0; j < JW; j++) {
      int row = wc * (TN / 2) + j * 16 + lc;
      bv[j] = *(const bf8v*)(Bl + cur * BBUF + row * 32 + lr * 8);
    }
#pragma unroll
    for (int i = 0; i < 4; i++)
#pragma unroll
      for (int j = 0; j < JW; j++)
        acc[i][j] = __builtin_amdgcn_mfma_f32_16x16x32_bf16(av[i], bv[j], acc[i][j], 0, 0, 0);
  }

#pragma unroll
  for (int j = 0; j < JW; j++) {
    int n = n0 + wc * (TN / 2) + j * 16 + lc;
    float bj = bias[n];
#pragma unroll
    for (int i = 0; i < 4; i++) {
      int mb = m0 + wr * 64 + i * 16 + lr * 4;
#pragma unroll
      for (int q = 0; q < 4; q++) {
        float val = fmaxf(acc[i][j][q] + bj, 0.0f);
        int m = mb + q;
        int s = m & 2047, b = m >> 11;          // A rows are b*2048+s
        out[(size_t)(s * 2 + b) * 1024 + n] = val;
      }
    }
  }
}

__global__ __launch_bounds__(256) void out_gemm(
    const unsigned short* __restrict__ Y, const unsigned short* __restrict__ Wo,
    const float* __restrict__ bo, float* __restrict__ out) {
  __shared__ __align__(16) unsigned short Al[2 * 4096];
  __shared__ __align__(16) unsigned short Bl[2 * 2048];
  gemm_body2<64>(Al, Bl, Y, Wo, bo, out);
}

// ---------------- flash attention (R8 config: dual-subtile waves, SPL=2) ----------------
__global__ __launch_bounds__(256, 2) void attn_kernel(
    const unsigned short* __restrict__ Qh, const unsigned short* __restrict__ Kh,
    const unsigned short* __restrict__ Vt,
    unsigned short* __restrict__ PO, float2* __restrict__ ML, int kvlen) {
  __shared__ __align__(16) unsigned short Kl[2][4096];
  __shared__ __align__(16) unsigned short Vl[2][4096];
  const int tid = threadIdx.x, w = tid >> 6, l = tid & 63;
  const int lo = l & 31, hi = l >> 5;
  const int bh = blockIdx.y;
  const int z = blockIdx.z;
  const int tbeg = z * kvlen, tend = tbeg + kvlen;
  const int q0 = blockIdx.x * 256 + w * 64;
  const size_t qkbase = (size_t)bh * 2048 * 64;
  const size_t vtbase = (size_t)bh * 64 * 2048;
  const float cs = 0.125f * 1.44269504088896341f;  // 1/sqrt(64) * log2(e)

  bf8v qf[2][4];
#pragma unroll
  for (int s = 0; s < 2; s++)
#pragma unroll
    for (int c = 0; c < 4; c++)
      qf[s][c] = *(const bf8v*)(Qh + qkbase + (size_t)(q0 + s * 32 + lo) * 64 + c * 16 + hi * 8);

  f16v oacc[2][2];
  oacc[0][0] = (f16v)(0.0f); oacc[0][1] = (f16v)(0.0f);
  oacc[1][0] = (f16v)(0.0f); oacc[1][1] = (f16v)(0.0f);
  float mrun[2] = {-1e30f, -1e30f};
  float lrun[2] = {0.0f, 0.0f};

  const int swl = (lo & 7) << 4;
  int akb[4], avb[2][2][2];
#pragma unroll
  for (int c = 0; c < 4; c++) akb[c] = lo * 128 + ((c * 32 + hi * 16) ^ swl);
#pragma unroll
  for (int dt = 0; dt < 2; dt++)
#pragma unroll
    for (int kvh = 0; kvh < 2; kvh++)
#pragma unroll
      for (int kc = 0; kc < 2; kc++)
        avb[dt][kvh][kc] = (dt * 32 + lo) * 128 + ((kvh * 64 + kc * 32 + hi * 16) ^ swl);

  int stE[2], stD[2], stKV[2];
#pragma unroll
  for (int i = 0; i < 2; i++) {
    int o = (w * 2 + i) * 1024 + l * 16;
    int row = o >> 7;
    stE[i] = (o ^ ((row & 7) << 4)) >> 1;
    stD[i] = stE[i] >> 6;
    stKV[i] = stE[i] & 63;
  }
  const char* KlB = (const char*)&Kl[0][0];
  const char* VlB = (const char*)&Vl[0][0];

  auto STAGE = [&](int buf, int t0) {
#pragma unroll
    for (int i = 0; i < 2; i++) {
      gload16(Kh + qkbase + (size_t)t0 * 64 + stE[i], (char*)&Kl[buf][0] + (w * 2 + i) * 1024);
      gload16(Vt + vtbase + (size_t)stD[i] * 2048 + t0 + stKV[i], (char*)&Vl[buf][0] + (w * 2 + i) * 1024);
    }
  };

  auto COMPUTE = [&](int bo) {
#pragma unroll
    for (int kvh = 0; kvh < 2; kvh++) {
      bf8v kf[4];
#pragma unroll
      for (int c = 0; c < 4; c++)
        kf[c] = *(const bf8v*)(KlB + bo + kvh * 4096 + akb[c]);
      f16v sa = (f16v)(0.0f), sb = (f16v)(0.0f);
      __builtin_amdgcn_s_setprio(1);
#pragma unroll
      for (int c = 0; c < 4; c++) {
        sa = __builtin_amdgcn_mfma_f32_32x32x16_bf16(kf[c], qf[0][c], sa, 0, 0, 0);
        sb = __builtin_amdgcn_mfma_f32_32x32x16_bf16(kf[c], qf[1][c], sb, 0, 0, 0);
      }
      __builtin_amdgcn_s_setprio(0);
      bf8v vf[2][2];
#pragma unroll
      for (int dt = 0; dt < 2; dt++)
#pragma unroll
        for (int kc = 0; kc < 2; kc++)
          vf[dt][kc] = *(const bf8v*)(VlB + bo + avb[dt][kvh][kc]);

#pragma unroll
      for (int s = 0; s < 2; s++) {
        const f16v& sc16 = (s == 0) ? sa : sb;
        float t0 = fmaxf(fmaxf(sc16[0], sc16[1]), sc16[2]);
        float t1 = fmaxf(fmaxf(sc16[3], sc16[4]), sc16[5]);
        float t2 = fmaxf(fmaxf(sc16[6], sc16[7]), sc16[8]);
        float t3 = fmaxf(fmaxf(sc16[9], sc16[10]), sc16[11]);
        float t4 = fmaxf(fmaxf(sc16[12], sc16[13]), sc16[14]);
        float lm = fmaxf(fmaxf(fmaxf(t0, t1), fmaxf(t2, t3)), fmaxf(t4, sc16[15]));
        float msc = lm * cs;
        if (!__all(msc <= mrun[s] + 5.0f)) {
          float x = msc, y = msc;
          PAIR_SWAP(x, y);
          float pm = fmaxf(x, y);
          float mnew = fmaxf(mrun[s], pm);
          float scl = __builtin_amdgcn_exp2f(mrun[s] - mnew);
          lrun[s] *= scl;
#pragma unroll
          for (int dt = 0; dt < 2; dt++)
#pragma unroll
            for (int r = 0; r < 16; r++) oacc[s][dt][r] *= scl;
          mrun[s] = mnew;
        }
        float p[16];
#pragma unroll
        for (int r = 0; r < 16; r++)
          p[r] = __builtin_amdgcn_exp2f(sc16[r] * cs - mrun[s]);
        float s01 = (p[0] + p[1]) + (p[2] + p[3]);
        float s23 = (p[4] + p[5]) + (p[6] + p[7]);
        float s45 = (p[8] + p[9]) + (p[10] + p[11]);
        float s67 = (p[12] + p[13]) + (p[14] + p[15]);
        lrun[s] += (s01 + s23) + (s45 + s67);
        bf8v pf[2];
#pragma unroll
        for (int kc = 0; kc < 2; kc++) {
          unsigned a0 = cvtpk(p[kc * 8 + 0], p[kc * 8 + 1]);
          unsigned a1 = cvtpk(p[kc * 8 + 2], p[kc * 8 + 3]);
          unsigned b0 = cvtpk(p[kc * 8 + 4], p[kc * 8 + 5]);
          unsigned b1 = cvtpk(p[kc * 8 + 6], p[kc * 8 + 7]);
          PAIR_SWAP(a0, b0);
          PAIR_SWAP(a1, b1);
          u4v pw;
          pw[0] = a0; pw[1] = a1; pw[2] = b0; pw[3] = b1;
          pf[kc] = __builtin_bit_cast(bf8v, pw);
        }
        __builtin_amdgcn_s_setprio(1);
#pragma unroll
        for (int dt = 0; dt < 2; dt++)
#pragma unroll
          for (int kc = 0; kc < 2; kc++)
            oacc[s][dt] = __builtin_amdgcn_mfma_f32_32x32x16_bf16(vf[dt][kc], pf[kc],
                                                                 oacc[s][dt], 0, 0, 0);
        __builtin_amdgcn_s_setprio(0);
      }
    }
  };

  STAGE(0, tbeg);
  __syncthreads();
#pragma unroll 1
  for (int t0 = tbeg; t0 < tend; t0 += 128) {
    STAGE(1, t0 + 64);
    COMPUTE(0);
    __syncthreads();
    if (t0 + 128 < tend) STAGE(0, t0 + 128);
    COMPUTE(8192);
    __syncthreads();
  }

  // epilogue: pair-total sums, NORMALIZE, write fp16 partials.
#pragma unroll
  for (int s = 0; s < 2; s++) {
    float x = lrun[s], y = lrun[s];
    PAIR_SWAP(x, y);
    float lt = x + y;
    float inv = 1.0f / lt;
    int q = q0 + s * 32 + lo;
    size_t prow = (size_t)(z * 32 + bh) * 2048 + q;
    if (hi == 0) ML[prow] = float2{mrun[s], lt};
    unsigned short* pp = PO + prow * 64;
#pragma unroll
    for (int dt = 0; dt < 2; dt++)
#pragma unroll
      for (int r = 0; r < 16; r++) {
        int d = dt * 32 + (r & 3) + 8 * (r >> 2) + 4 * hi;
        pp[d] = f2h(oacc[s][dt][r] * inv);
      }
  }
}

// ---------------- combine 2 normalized fp16 partials -> Y (B,S,D) bf16 ----------------
__global__ __launch_bounds__(256) void combine_kernel(
    const unsigned short* __restrict__ PO, const float2* __restrict__ ML,
    unsigned short* __restrict__ Y) {
  int idx = blockIdx.x * 256 + threadIdx.x;
  int row = idx >> 1, hr = idx & 1;
  int bh = row >> 11, q = row & 2047;
  float2 ml0 = ML[row], ml1 = ML[65536 + row];
  float M = fmaxf(ml0.x, ml1.x);
  float w0 = ml0.y * __builtin_amdgcn_exp2f(ml0.x - M);
  float w1 = ml1.y * __builtin_amdgcn_exp2f(ml1.x - M);
  float invW = 1.0f / (w0 + w1);
  w0 *= invW; w1 *= invW;
  int b = bh >> 4, h = bh & 15;
  unsigned short* yp = Y + (((size_t)(b * 2048 + q)) << 10) + h * 64 + hr * 32;
  const unsigned short* p0 = PO + (size_t)row * 64 + hr * 32;
  const unsigned short* p1 = PO + ((size_t)65536 + row) * 64 + hr * 32;
#pragma unroll
  for (int g = 0; g < 4; g++) {
    bf8v v0 = *(const bf8v*)(p0 + g * 8);
    bf8v v1 = *(const bf8v*)(p1 + g * 8);
    bf8v r;
#pragma unroll
    for (int j = 0; j < 8; j++)
      r[j] = (short)f2bf(h2f((unsigned short)v0[j]) * w0 +
                         h2f((unsigned short)v1[j]) * w1);
    *(bf8v*)(yp + g * 8) = r;
  }
}

// ---------------- launch ----------------
extern "C" void kernel_launch(void* const* d_in, const int* in_sizes, int n_in,
                              void* d_out, int out_size, void* d_ws, size_t ws_size,
                              hipStream_t stream) {
  const float* q  = (const float*)d_in[0];
  const float* k  = (const float*)d_in[1];
  const float* v  = (const float*)d_in[2];
  const float* Wq = (const float*)d_in[3];
  const float* Wk = (const float*)d_in[4];
  const float* Wv = (const float*)d_in[5];
  const float* Wo = (const float*)d_in[6];
  const float* bq = (const float*)d_in[7];
  const float* bk = (const float*)d_in[8];
  const float* bv = (const float*)d_in[9];
  const float* bo = (const float*)d_in[10];

  const size_t NA = (size_t)4096 * 1024;   // 4M elems
  const size_t NW = (size_t)1024 * 1024;
  unsigned short* WqB = (unsigned short*)d_ws;   // weights bf16, contiguous
  unsigned short* WkB = WqB + NW;
  unsigned short* WvB = WkB + NW;
  unsigned short* WoB = WvB + NW;
  unsigned short* Qh  = WoB + NW;
  unsigned short* Kh  = Qh  + NA;
  unsigned short* Vt  = Kh  + NA;
  unsigned short* Y   = Vt  + NA;
  unsigned short* PO  = Y   + NA;          // 2 * 4M fp16 = 16 MB
  float2*         ML  = (float2*)(PO + 2 * NA);   // 2 * 64K float2 = 1 MB

  cvt_w<<<dim3(2048), 256, 0, stream>>>(Wq, Wk, Wv, Wo, WqB);

  qkv_gemm<<<dim3(32, 8, 3), 256, 0, stream>>>(q, k, v, WqB, WkB, WvB,
                                               bq, bk, bv, Qh, Kh, Vt);
  attn_kernel<<<dim3(8, 32, 2), 256, 0, stream>>>(Qh, Kh, Vt, PO, ML, 1024);
  combine_kernel<<<dim3(512), 256, 0, stream>>>(PO, ML, Y);
  out_gemm<<<dim3(32, 16), 256, 0, stream>>>(Y, WoB, bo, (float*)d_out);
}

// Round 11
// 123.257 us; speedup vs baseline: 1.1191x; 1.0348x over previous
//
#include <hip/hip_runtime.h>
#include <stdint.h>

typedef __attribute__((ext_vector_type(8))) short bf8v;   // 8 bf16/f16 raw bits (4 VGPRs)
typedef __attribute__((ext_vector_type(4))) float f4v;
typedef __attribute__((ext_vector_type(16))) float f16v;
typedef __attribute__((ext_vector_type(4))) unsigned int u4v;

__device__ __forceinline__ unsigned short f2bf(float f) {
  unsigned int u = __float_as_uint(f);
  u += 0x7fffu + ((u >> 16) & 1u);   // round-to-nearest-even
  return (unsigned short)(u >> 16);
}

__device__ __forceinline__ unsigned short f2h(float f) {
  _Float16 h = (_Float16)f;
  return __builtin_bit_cast(unsigned short, h);
}

__device__ __forceinline__ float h2f(unsigned short s) {
  return (float)__builtin_bit_cast(_Float16, s);
}

__device__ __forceinline__ void gload16(const void* g, void* l) {
  __builtin_amdgcn_global_load_lds(
      (__attribute__((address_space(1))) void*)reinterpret_cast<uintptr_t>(g),
      (__attribute__((address_space(3))) void*)reinterpret_cast<uintptr_t>(l),
      16, 0, 0);
}

__device__ __forceinline__ unsigned cvtpk(float lo, float hi) {
  unsigned r;
  asm("v_cvt_pk_bf16_f32 %0, %1, %2" : "=v"(r) : "v"(lo), "v"(hi));
  return r;
}

// pairwise lane<->lane^32 exchange; with x=y=v: x={v.lo,v.lo}, y={v.hi,v.hi}
#define PAIR_SWAP(x, y) asm("v_permlane32_swap_b32 %0, %1" : "+v"(x), "+v"(y))

// ---------------- fp32 -> bf16 conversion: WEIGHTS ONLY (4 x 1M elems) ----------------
__global__ __launch_bounds__(256) void cvt_w(
    const float* __restrict__ s0, const float* __restrict__ s1,
    const float* __restrict__ s2, const float* __restrict__ s3,
    unsigned short* __restrict__ dst) {
  const size_t NW = (size_t)1 << 20;
  size_t i = ((size_t)blockIdx.x * 256 + threadIdx.x) * 8;
  int a = (int)(i >> 20);
  const float* src = (a == 0) ? s0 : (a == 1) ? s1 : (a == 2) ? s2 : s3;
  size_t off = i & (NW - 1);
  const f4v* sp = (const f4v*)(src + off);
  f4v x = sp[0], y = sp[1];
  bf8v r;
  r[0] = (short)f2bf(x[0]); r[1] = (short)f2bf(x[1]);
  r[2] = (short)f2bf(x[2]); r[3] = (short)f2bf(x[3]);
  r[4] = (short)f2bf(y[0]); r[5] = (short)f2bf(y[1]);
  r[6] = (short)f2bf(y[2]); r[7] = (short)f2bf(y[3]);
  *(bf8v*)(dst + i) = r;
}

// ---------------- qkv GEMM: A fp32 reg-staged w/ in-flight cvt, W bf16 via gload_lds ----------------
// A: (4096,1024) fp32 row-major (rows m = s*2+b).  W: (1024,1024) bf16 (n,k).
// LDS identical to the proven m97 structure (bf16 [128][32] per operand buffer,
// 32 KB total); A conversion happens in REGISTERS during staging, so the
// fragment path (4x ds_read_b128 per wave) is unchanged. (R10's fp32-in-LDS
// variant grew LDS to 48KB and doubled fragment ds_reads -> 3x qkv slowdown.)
// OMODE 0: out bf16 (B,H,S,64).  OMODE 1: out bf16 (B,H,64,S) [V transposed].
template <int OMODE>
__device__ __forceinline__ void gemmA32r_body(
    unsigned short* Al, unsigned short* Bl,
    const float* __restrict__ A, const unsigned short* __restrict__ W,
    const float* __restrict__ bias, unsigned short* __restrict__ out) {
  const int tid = threadIdx.x;
  const int w = tid >> 6, l = tid & 63;
  const int lr = l >> 4, lc = l & 15;
  const int m0 = blockIdx.x * 128, n0 = blockIdx.y * 128;
  const int wr = w >> 1, wc = w & 1;

  f4v acc[4][4];
#pragma unroll
  for (int i = 0; i < 4; i++)
#pragma unroll
    for (int j = 0; j < 4; j++) acc[i][j] = (f4v)(0.0f);

  // per-thread A staging coords: 2 chunks x 8 contiguous elems
  int eA[2], rA[2], kA[2];
#pragma unroll
  for (int i = 0; i < 2; i++) {
    int chunk = w * 2 + i;
    eA[i] = chunk * 512 + l * 8;
    rA[i] = eA[i] >> 5;
    kA[i] = eA[i] & 31;
  }

  const int NK = 32;
  f4v ar[2][2];

  auto A_LOAD = [&](int kk) {
#pragma unroll
    for (int i = 0; i < 2; i++) {
      const float* s = A + (size_t)(m0 + rA[i]) * 1024 + kk * 32 + kA[i];
      ar[i][0] = *(const f4v*)s;
      ar[i][1] = *(const f4v*)(s + 4);
    }
  };
  auto A_WRITE = [&](int buf) {
#pragma unroll
    for (int i = 0; i < 2; i++) {
      u4v aw;
      aw[0] = cvtpk(ar[i][0][0], ar[i][0][1]);
      aw[1] = cvtpk(ar[i][0][2], ar[i][0][3]);
      aw[2] = cvtpk(ar[i][1][0], ar[i][1][1]);
      aw[3] = cvtpk(ar[i][1][2], ar[i][1][3]);
      *(bf8v*)(Al + buf * 4096 + eA[i]) = __builtin_bit_cast(bf8v, aw);
    }
  };
  auto B_STAGE = [&](int buf, int kk) {
#pragma unroll
    for (int i = 0; i < 2; i++) {
      int chunk = w * 2 + i;
      int e = chunk * 512 + l * 8;
      int r = e >> 5, k = e & 31;
      gload16(W + (size_t)(n0 + r) * 1024 + kk * 32 + k, Bl + buf * 4096 + chunk * 512);
    }
  };

  // prologue: stage kk=0 into buffer 0
  A_LOAD(0);
  B_STAGE(0, 0);
  A_WRITE(0);
  __syncthreads();

  for (int kk = 0; kk < NK; kk++) {
    const int cur = kk & 1;
    const bool more = (kk + 1 < NK);
    if (more) {
      A_LOAD(kk + 1);            // latency hides under the MFMAs below
      B_STAGE(cur ^ 1, kk + 1);
    }
    bf8v av[4], bv[4];
#pragma unroll
    for (int i = 0; i < 4; i++) {
      int row = wr * 64 + i * 16 + lc;
      av[i] = *(const bf8v*)(Al + cur * 4096 + row * 32 + lr * 8);
    }
#pragma unroll
    for (int j = 0; j < 4; j++) {
      int row = wc * 64 + j * 16 + lc;
      bv[j] = *(const bf8v*)(Bl + cur * 4096 + row * 32 + lr * 8);
    }
#pragma unroll
    for (int i = 0; i < 4; i++)
#pragma unroll
      for (int j = 0; j < 4; j++)
        acc[i][j] = __builtin_amdgcn_mfma_f32_16x16x32_bf16(av[i], bv[j], acc[i][j], 0, 0, 0);
    if (more) A_WRITE(cur ^ 1);  // cur^1 not read this iter; barrier orders for next
    __syncthreads();
  }

  // epilogue: bias + ReLU + layout store
#pragma unroll
  for (int j = 0; j < 4; j++) {
    int n = n0 + wc * 64 + j * 16 + lc;
    float bj = bias[n];
#pragma unroll
    for (int i = 0; i < 4; i++) {
      int mb = m0 + wr * 64 + i * 16 + lr * 4;
#pragma unroll
      for (int q = 0; q < 4; q++) {
        float val = fmaxf(acc[i][j][q] + bj, 0.0f);
        int m = mb + q;
        int s = m >> 1, b = m & 1;
        int h = n >> 6, d = n & 63;
        if (OMODE == 0)
          out[((size_t)(b * 16 + h) * 2048 + s) * 64 + d] = f2bf(val);
        else
          out[((size_t)(b * 16 + h) * 64 + d) * 2048 + s] = f2bf(val);
      }
    }
  }
}

__global__ __launch_bounds__(256) void qkv_gemm(
    const float* __restrict__ qA, const float* __restrict__ kA,
    const float* __restrict__ vA,
    const unsigned short* __restrict__ Wq, const unsigned short* __restrict__ Wk,
    const unsigned short* __restrict__ Wv,
    const float* __restrict__ bq, const float* __restrict__ bk,
    const float* __restrict__ bv,
    unsigned short* __restrict__ Qh, unsigned short* __restrict__ Kh,
    unsigned short* __restrict__ Vt) {
  __shared__ __align__(16) unsigned short Al[2 * 4096];   // 16 KB
  __shared__ __align__(16) unsigned short Bl[2 * 4096];   // 16 KB
  int z = blockIdx.z;
  if (z == 0)      gemmA32r_body<0>(Al, Bl, qA, Wq, bq, Qh);
  else if (z == 1) gemmA32r_body<0>(Al, Bl, kA, Wk, bk, Kh);
  else             gemmA32r_body<1>(Al, Bl, vA, Wv, bv, Vt);
}

// ---------------- bf16-A GEMM body (m97 structure), used by out_gemm ----------------
template <int TN>
__device__ __forceinline__ void gemm_body2(
    unsigned short* Al, unsigned short* Bl,
    const unsigned short* __restrict__ A, const unsigned short* __restrict__ W,
    const float* __restrict__ bias, float* __restrict__ out) {
  const int tid = threadIdx.x;
  const int w = tid >> 6, l = tid & 63;
  const int lr = l >> 4, lc = l & 15;
  const int m0 = blockIdx.x * 128, n0 = blockIdx.y * TN;
  const int wr = w >> 1, wc = w & 1;
  const int JW = TN / 32;
  const int BCPW = TN / 64;
  const int BBUF = TN * 32;

  f4v acc[4][JW];
#pragma unroll
  for (int i = 0; i < 4; i++)
#pragma unroll
    for (int j = 0; j < JW; j++) acc[i][j] = (f4v)(0.0f);

  const int NK = 32;
#pragma unroll
  for (int i = 0; i < 2; i++) {
    int chunk = w * 2 + i;
    int e = chunk * 512 + l * 8;
    int r = e >> 5, k = e & 31;
    gload16(A + (size_t)(m0 + r) * 1024 + k, Al + chunk * 512);
  }
#pragma unroll
  for (int i = 0; i < BCPW; i++) {
    int chunk = w * BCPW + i;
    int e = chunk * 512 + l * 8;
    int r = e >> 5, k = e & 31;
    gload16(W + (size_t)(n0 + r) * 1024 + k, Bl + chunk * 512);
  }

  for (int kk = 0; kk < NK; kk++) {
    const int cur = kk & 1;
    __syncthreads();
    if (kk + 1 < NK) {
#pragma unroll
      for (int i = 0; i < 2; i++) {
        int chunk = w * 2 + i;
        int e = chunk * 512 + l * 8;
        int r = e >> 5, k = (kk + 1) * 32 + (e & 31);
        gload16(A + (size_t)(m0 + r) * 1024 + k, Al + (cur ^ 1) * 4096 + chunk * 512);
      }
#pragma unroll
      for (int i = 0; i < BCPW; i++) {
        int chunk = w * BCPW + i;
        int e = chunk * 512 + l * 8;
        int r = e >> 5, k = (kk + 1) * 32 + (e & 31);
        gload16(W + (size_t)(n0 + r) * 1024 + k, Bl + (cur ^ 1) * BBUF + chunk * 512);
      }
    }
    bf8v av[4], bv[JW];
#pragma unroll
    for (int i = 0; i < 4; i++) {
      int row = wr * 64 + i * 16 + lc;
      av[i] = *(const bf8v*)(Al + cur * 4096 + row * 32 + lr * 8);
    }
#pragma unroll
    for (int j = 0; j < JW; j++) {
      int row = wc * (TN / 2) + j * 16 + lc;
      bv[j] = *(const bf8v*)(Bl + cur * BBUF + row * 32 + lr * 8);
    }
#pragma unroll
    for (int i = 0; i < 4; i++)
#pragma unroll
      for (int j = 0; j < JW; j++)
        acc[i][j] = __builtin_amdgcn_mfma_f32_16x16x32_bf16(av[i], bv[j], acc[i][j], 0, 0, 0);
  }

#pragma unroll
  for (int j = 0; j < JW; j++) {
    int n = n0 + wc * (TN / 2) + j * 16 + lc;
    float bj = bias[n];
#pragma unroll
    for (int i = 0; i < 4; i++) {
      int mb = m0 + wr * 64 + i * 16 + lr * 4;
#pragma unroll
      for (int q = 0; q < 4; q++) {
        float val = fmaxf(acc[i][j][q] + bj, 0.0f);
        int m = mb + q;
        int s = m & 2047, b = m >> 11;          // A rows are b*2048+s
        out[(size_t)(s * 2 + b) * 1024 + n] = val;
      }
    }
  }
}

__global__ __launch_bounds__(256) void out_gemm(
    const unsigned short* __restrict__ Y, const unsigned short* __restrict__ Wo,
    const float* __restrict__ bo, float* __restrict__ out) {
  __shared__ __align__(16) unsigned short Al[2 * 4096];
  __shared__ __align__(16) unsigned short Bl[2 * 2048];
  gemm_body2<64>(Al, Bl, Y, Wo, bo, out);
}

// ---------------- flash attention (R8 config: dual-subtile waves, SPL=2) ----------------
__global__ __launch_bounds__(256, 2) void attn_kernel(
    const unsigned short* __restrict__ Qh, const unsigned short* __restrict__ Kh,
    const unsigned short* __restrict__ Vt,
    unsigned short* __restrict__ PO, float2* __restrict__ ML, int kvlen) {
  __shared__ __align__(16) unsigned short Kl[2][4096];
  __shared__ __align__(16) unsigned short Vl[2][4096];
  const int tid = threadIdx.x, w = tid >> 6, l = tid & 63;
  const int lo = l & 31, hi = l >> 5;
  const int bh = blockIdx.y;
  const int z = blockIdx.z;
  const int tbeg = z * kvlen, tend = tbeg + kvlen;
  const int q0 = blockIdx.x * 256 + w * 64;
  const size_t qkbase = (size_t)bh * 2048 * 64;
  const size_t vtbase = (size_t)bh * 64 * 2048;
  const float cs = 0.125f * 1.44269504088896341f;  // 1/sqrt(64) * log2(e)

  bf8v qf[2][4];
#pragma unroll
  for (int s = 0; s < 2; s++)
#pragma unroll
    for (int c = 0; c < 4; c++)
      qf[s][c] = *(const bf8v*)(Qh + qkbase + (size_t)(q0 + s * 32 + lo) * 64 + c * 16 + hi * 8);

  f16v oacc[2][2];
  oacc[0][0] = (f16v)(0.0f); oacc[0][1] = (f16v)(0.0f);
  oacc[1][0] = (f16v)(0.0f); oacc[1][1] = (f16v)(0.0f);
  float mrun[2] = {-1e30f, -1e30f};
  float lrun[2] = {0.0f, 0.0f};

  const int swl = (lo & 7) << 4;
  int akb[4], avb[2][2][2];
#pragma unroll
  for (int c = 0; c < 4; c++) akb[c] = lo * 128 + ((c * 32 + hi * 16) ^ swl);
#pragma unroll
  for (int dt = 0; dt < 2; dt++)
#pragma unroll
    for (int kvh = 0; kvh < 2; kvh++)
#pragma unroll
      for (int kc = 0; kc < 2; kc++)
        avb[dt][kvh][kc] = (dt * 32 + lo) * 128 + ((kvh * 64 + kc * 32 + hi * 16) ^ swl);

  int stE[2], stD[2], stKV[2];
#pragma unroll
  for (int i = 0; i < 2; i++) {
    int o = (w * 2 + i) * 1024 + l * 16;
    int row = o >> 7;
    stE[i] = (o ^ ((row & 7) << 4)) >> 1;
    stD[i] = stE[i] >> 6;
    stKV[i] = stE[i] & 63;
  }
  const char* KlB = (const char*)&Kl[0][0];
  const char* VlB = (const char*)&Vl[0][0];

  auto STAGE = [&](int buf, int t0) {
#pragma unroll
    for (int i = 0; i < 2; i++) {
      gload16(Kh + qkbase + (size_t)t0 * 64 + stE[i], (char*)&Kl[buf][0] + (w * 2 + i) * 1024);
      gload16(Vt + vtbase + (size_t)stD[i] * 2048 + t0 + stKV[i], (char*)&Vl[buf][0] + (w * 2 + i) * 1024);
    }
  };

  auto COMPUTE = [&](int bo) {
#pragma unroll
    for (int kvh = 0; kvh < 2; kvh++) {
      bf8v kf[4];
#pragma unroll
      for (int c = 0; c < 4; c++)
        kf[c] = *(const bf8v*)(KlB + bo + kvh * 4096 + akb[c]);
      f16v sa = (f16v)(0.0f), sb = (f16v)(0.0f);
      __builtin_amdgcn_s_setprio(1);
#pragma unroll
      for (int c = 0; c < 4; c++) {
        sa = __builtin_amdgcn_mfma_f32_32x32x16_bf16(kf[c], qf[0][c], sa, 0, 0, 0);
        sb = __builtin_amdgcn_mfma_f32_32x32x16_bf16(kf[c], qf[1][c], sb, 0, 0, 0);
      }
      __builtin_amdgcn_s_setprio(0);
      bf8v vf[2][2];
#pragma unroll
      for (int dt = 0; dt < 2; dt++)
#pragma unroll
        for (int kc = 0; kc < 2; kc++)
          vf[dt][kc] = *(const bf8v*)(VlB + bo + avb[dt][kvh][kc]);

#pragma unroll
      for (int s = 0; s < 2; s++) {
        const f16v& sc16 = (s == 0) ? sa : sb;
        float t0 = fmaxf(fmaxf(sc16[0], sc16[1]), sc16[2]);
        float t1 = fmaxf(fmaxf(sc16[3], sc16[4]), sc16[5]);
        float t2 = fmaxf(fmaxf(sc16[6], sc16[7]), sc16[8]);
        float t3 = fmaxf(fmaxf(sc16[9], sc16[10]), sc16[11]);
        float t4 = fmaxf(fmaxf(sc16[12], sc16[13]), sc16[14]);
        float lm = fmaxf(fmaxf(fmaxf(t0, t1), fmaxf(t2, t3)), fmaxf(t4, sc16[15]));
        float msc = lm * cs;
        if (!__all(msc <= mrun[s] + 5.0f)) {
          float x = msc, y = msc;
          PAIR_SWAP(x, y);
          float pm = fmaxf(x, y);
          float mnew = fmaxf(mrun[s], pm);
          float scl = __builtin_amdgcn_exp2f(mrun[s] - mnew);
          lrun[s] *= scl;
#pragma unroll
          for (int dt = 0; dt < 2; dt++)
#pragma unroll
            for (int r = 0; r < 16; r++) oacc[s][dt][r] *= scl;
          mrun[s] = mnew;
        }
        float p[16];
#pragma unroll
        for (int r = 0; r < 16; r++)
          p[r] = __builtin_amdgcn_exp2f(sc16[r] * cs - mrun[s]);
        float s01 = (p[0] + p[1]) + (p[2] + p[3]);
        float s23 = (p[4] + p[5]) + (p[6] + p[7]);
        float s45 = (p[8] + p[9]) + (p[10] + p[11]);
        float s67 = (p[12] + p[13]) + (p[14] + p[15]);
        lrun[s] += (s01 + s23) + (s45 + s67);
        bf8v pf[2];
#pragma unroll
        for (int kc = 0; kc < 2; kc++) {
          unsigned a0 = cvtpk(p[kc * 8 + 0], p[kc * 8 + 1]);
          unsigned a1 = cvtpk(p[kc * 8 + 2], p[kc * 8 + 3]);
          unsigned b0 = cvtpk(p[kc * 8 + 4], p[kc * 8 + 5]);
          unsigned b1 = cvtpk(p[kc * 8 + 6], p[kc * 8 + 7]);
          PAIR_SWAP(a0, b0);
          PAIR_SWAP(a1, b1);
          u4v pw;
          pw[0] = a0; pw[1] = a1; pw[2] = b0; pw[3] = b1;
          pf[kc] = __builtin_bit_cast(bf8v, pw);
        }
        __builtin_amdgcn_s_setprio(1);
#pragma unroll
        for (int dt = 0; dt < 2; dt++)
#pragma unroll
          for (int kc = 0; kc < 2; kc++)
            oacc[s][dt] = __builtin_amdgcn_mfma_f32_32x32x16_bf16(vf[dt][kc], pf[kc],
                                                                 oacc[s][dt], 0, 0, 0);
        __builtin_amdgcn_s_setprio(0);
      }
    }
  };

  STAGE(0, tbeg);
  __syncthreads();
#pragma unroll 1
  for (int t0 = tbeg; t0 < tend; t0 += 128) {
    STAGE(1, t0 + 64);
    COMPUTE(0);
    __syncthreads();
    if (t0 + 128 < tend) STAGE(0, t0 + 128);
    COMPUTE(8192);
    __syncthreads();
  }

  // epilogue: pair-total sums, NORMALIZE, write fp16 partials.
#pragma unroll
  for (int s = 0; s < 2; s++) {
    float x = lrun[s], y = lrun[s];
    PAIR_SWAP(x, y);
    float lt = x + y;
    float inv = 1.0f / lt;
    int q = q0 + s * 32 + lo;
    size_t prow = (size_t)(z * 32 + bh) * 2048 + q;
    if (hi == 0) ML[prow] = float2{mrun[s], lt};
    unsigned short* pp = PO + prow * 64;
#pragma unroll
    for (int dt = 0; dt < 2; dt++)
#pragma unroll
      for (int r = 0; r < 16; r++) {
        int d = dt * 32 + (r & 3) + 8 * (r >> 2) + 4 * hi;
        pp[d] = f2h(oacc[s][dt][r] * inv);
      }
  }
}

// ---------------- combine 2 normalized fp16 partials -> Y (B,S,D) bf16 ----------------
__global__ __launch_bounds__(256) void combine_kernel(
    const unsigned short* __restrict__ PO, const float2* __restrict__ ML,
    unsigned short* __restrict__ Y) {
  int idx = blockIdx.x * 256 + threadIdx.x;
  int row = idx >> 1, hr = idx & 1;
  int bh = row >> 11, q = row & 2047;
  float2 ml0 = ML[row], ml1 = ML[65536 + row];
  float M = fmaxf(ml0.x, ml1.x);
  float w0 = ml0.y * __builtin_amdgcn_exp2f(ml0.x - M);
  float w1 = ml1.y * __builtin_amdgcn_exp2f(ml1.x - M);
  float invW = 1.0f / (w0 + w1);
  w0 *= invW; w1 *= invW;
  int b = bh >> 4, h = bh & 15;
  unsigned short* yp = Y + (((size_t)(b * 2048 + q)) << 10) + h * 64 + hr * 32;
  const unsigned short* p0 = PO + (size_t)row * 64 + hr * 32;
  const unsigned short* p1 = PO + ((size_t)65536 + row) * 64 + hr * 32;
#pragma unroll
  for (int g = 0; g < 4; g++) {
    bf8v v0 = *(const bf8v*)(p0 + g * 8);
    bf8v v1 = *(const bf8v*)(p1 + g * 8);
    bf8v r;
#pragma unroll
    for (int j = 0; j < 8; j++)
      r[j] = (short)f2bf(h2f((unsigned short)v0[j]) * w0 +
                         h2f((unsigned short)v1[j]) * w1);
    *(bf8v*)(yp + g * 8) = r;
  }
}

// ---------------- launch ----------------
extern "C" void kernel_launch(void* const* d_in, const int* in_sizes, int n_in,
                              void* d_out, int out_size, void* d_ws, size_t ws_size,
                              hipStream_t stream) {
  const float* q  = (const float*)d_in[0];
  const float* k  = (const float*)d_in[1];
  const float* v  = (const float*)d_in[2];
  const float* Wq = (const float*)d_in[3];
  const float* Wk = (const float*)d_in[4];
  const float* Wv = (const float*)d_in[5];
  const float* Wo = (const float*)d_in[6];
  const float* bq = (const float*)d_in[7];
  const float* bk = (const float*)d_in[8];
  const float* bv = (const float*)d_in[9];
  const float* bo = (const float*)d_in[10];

  const size_t NA = (size_t)4096 * 1024;   // 4M elems
  const size_t NW = (size_t)1024 * 1024;
  unsigned short* WqB = (unsigned short*)d_ws;   // weights bf16, contiguous
  unsigned short* WkB = WqB + NW;
  unsigned short* WvB = WkB + NW;
  unsigned short* WoB = WvB + NW;
  unsigned short* Qh  = WoB + NW;
  unsigned short* Kh  = Qh  + NA;
  unsigned short* Vt  = Kh  + NA;
  unsigned short* Y   = Vt  + NA;
  unsigned short* PO  = Y   + NA;          // 2 * 4M fp16 = 16 MB
  float2*         ML  = (float2*)(PO + 2 * NA);   // 2 * 64K float2 = 1 MB

  cvt_w<<<dim3(2048), 256, 0, stream>>>(Wq, Wk, Wv, Wo, WqB);

  qkv_gemm<<<dim3(32, 8, 3), 256, 0, stream>>>(q, k, v, WqB, WkB, WvB,
                                               bq, bk, bv, Qh, Kh, Vt);
  attn_kernel<<<dim3(8, 32, 2), 256, 0, stream>>>(Qh, Kh, Vt, PO, ML, 1024);
  combine_kernel<<<dim3(512), 256, 0, stream>>>(PO, ML, Y);
  out_gemm<<<dim3(32, 16), 256, 0, stream>>>(Y, WoB, bo, (float*)d_out);
}